// Round 7
// baseline (180.434 us; speedup 1.0000x reference)
//
#include <hip/hip_runtime.h>
#include <hip/hip_fp16.h>
#include <math.h>

#define NN 50000
#define NE 800000
#define FN 128
#define FE 32
#define HD 64
#define NB 49   // scan blocks: ceil(NN/1024)
#define GP ((NN + 127) / 128)    // proj blocks (128 rows each)
#define NT (NE / 64)             // 12500 64-edge tiles (NE % 64 == 0)
#define EB2 ((NT + 7) / 8)       // 1563 edge blocks: 4 waves x 2 tiles
#define GE ((NE + 255) / 256)    // scatter blocks

typedef unsigned long long u64;
typedef unsigned short u16;

// ---------------- K0: fold edge chains into v1,v2,v3 + zero deg --------------
__global__ void k_vecs_zero(const float* __restrict__ We1, const float* __restrict__ We2,
                            const float* __restrict__ We3, const float* __restrict__ ae1,
                            const float* __restrict__ ae2, const float* __restrict__ ae3,
                            float* __restrict__ v123, int* __restrict__ deg) {
  const int i = blockIdx.x * blockDim.x + threadIdx.x;
  if (i < NN) deg[i] = 0;
  if (blockIdx.x != 0) return;
  __shared__ float u2[HD], u3[HD], u23[HD];
  const int t = threadIdx.x;
  if (t < HD) {
    float s2 = 0.f, s3 = 0.f;
    for (int j = 0; j < HD; ++j) {
      s2 += We2[t * HD + j] * ae2[j];
      s3 += We3[t * HD + j] * ae3[j];
    }
    u2[t] = s2; u3[t] = s3;
  }
  __syncthreads();
  if (t < HD) {
    float s23 = 0.f;
    for (int j = 0; j < HD; ++j) s23 += We2[t * HD + j] * u3[j];
    u23[t] = s23;
  }
  __syncthreads();
  if (t < FE) {
    float a = 0.f, b = 0.f, c = 0.f;
    for (int j = 0; j < HD; ++j) {
      float w = We1[t * HD + j];
      a += w * ae1[j];
      b += w * u2[j];
      c += w * u23[j];
    }
    v123[t] = a; v123[32 + t] = b; v123[64 + t] = c;
  }
}

// ---- mega6: [0,EB2) edge blocks FIRST | [EB2,EB2+GP) LDS-free layer-1 GEMM --
// Edge path: R5's 8-lane-cooperative coalesced gather, but BOTH tiles' 16
// float4 loads are issued up-front into registers (atomics + index loads
// before them), doubling per-wave in-flight bytes (~16KB) at unchanged
// occupancy (VGPR stays in the <=128 / 4-waves-per-SIMD bucket). Tests the
// in-flight-bytes theory of the ~54 cyc/edge streaming floor.
__global__ __launch_bounds__(256) void k_mega6(
    const float* __restrict__ x, const float* __restrict__ W,
    const float* __restrict__ asv, const float* __restrict__ adv,
    __half* __restrict__ xph, float* __restrict__ ssrc, float* __restrict__ sdst,
    const int* __restrict__ srcA, const int* __restrict__ dstA,
    const float* __restrict__ eattr, const float* __restrict__ v123,
    int* __restrict__ deg, u16* __restrict__ rank, u64* __restrict__ trec) {
  const int t = threadIdx.x;
  if (blockIdx.x < EB2) {
    const int kb = blockIdx.x;
    const int w = t >> 6, lane = t & 63;
    const int g = lane >> 3, q = lane & 7;
    const float4 v1q = *(const float4*)(v123 + q * 4);
    const float4 v2q = *(const float4*)(v123 + 32 + q * 4);
    const float4 v3q = *(const float4*)(v123 + 64 + q * 4);
    const int perm = 8 * q + g;              // owned edge slot within a tile
    const int tA = kb * 8 + w * 2;
    const int tB = tA + 1;
    const bool okA = tA < NT, okB = tB < NT;
    const int eA = tA * 64 + perm, eB = tB * 64 + perm;

    int dA = 0, sA = 0, dB = 0, sB = 0, rA = 0, rB = 0;
    if (okA) { dA = dstA[eA]; sA = srcA[eA]; }
    if (okB) { dB = dstA[eB]; sB = srcA[eB]; }
    if (okA) rA = atomicAdd(&deg[dA], 1);    // oldest in vmcnt queue
    if (okB) rB = atomicAdd(&deg[dB], 1);

    float4 xa[8], xb[8];                     // 16 x 1KB wave-wide in flight
    if (okA) {
      const size_t b0 = (size_t)tA * 64;
#pragma unroll
      for (int k = 0; k < 8; ++k)
        xa[k] = *(const float4*)(eattr + (b0 + 8 * k + g) * FE + q * 4);
    }
    if (okB) {
      const size_t b1 = (size_t)tB * 64;
#pragma unroll
      for (int k = 0; k < 8; ++k)
        xb[k] = *(const float4*)(eattr + (b1 + 8 * k + g) * FE + q * 4);
    }

    if (okA) {
      float ra = 0.f, rb = 0.f, rc = 0.f;
#pragma unroll
      for (int k = 0; k < 8; ++k) {
        float a = xa[k].x * v1q.x + xa[k].y * v1q.y + xa[k].z * v1q.z + xa[k].w * v1q.w;
        float b = xa[k].x * v2q.x + xa[k].y * v2q.y + xa[k].z * v2q.z + xa[k].w * v2q.w;
        float c = xa[k].x * v3q.x + xa[k].y * v3q.y + xa[k].z * v3q.z + xa[k].w * v3q.w;
#pragma unroll
        for (int off = 1; off < 8; off <<= 1) {
          a += __shfl_xor(a, off);
          b += __shfl_xor(b, off);
          c += __shfl_xor(c, off);
        }
        if (q == k) { ra = a; rb = b; rc = c; }
      }
      trec[eA] = (u64)(u16)sA
               | ((u64)__half_as_ushort(__float2half_rn(ra)) << 16)
               | ((u64)__half_as_ushort(__float2half_rn(rb)) << 32)
               | ((u64)__half_as_ushort(__float2half_rn(rc)) << 48);
      rank[eA] = (u16)rA;
    }
    if (okB) {
      float ra = 0.f, rb = 0.f, rc = 0.f;
#pragma unroll
      for (int k = 0; k < 8; ++k) {
        float a = xb[k].x * v1q.x + xb[k].y * v1q.y + xb[k].z * v1q.z + xb[k].w * v1q.w;
        float b = xb[k].x * v2q.x + xb[k].y * v2q.y + xb[k].z * v2q.z + xb[k].w * v2q.w;
        float c = xb[k].x * v3q.x + xb[k].y * v3q.y + xb[k].z * v3q.z + xb[k].w * v3q.w;
#pragma unroll
        for (int off = 1; off < 8; off <<= 1) {
          a += __shfl_xor(a, off);
          b += __shfl_xor(b, off);
          c += __shfl_xor(c, off);
        }
        if (q == k) { ra = a; rb = b; rc = c; }
      }
      trec[eB] = (u64)(u16)sB
               | ((u64)__half_as_ushort(__float2half_rn(ra)) << 16)
               | ((u64)__half_as_ushort(__float2half_rn(rb)) << 32)
               | ((u64)__half_as_ushort(__float2half_rn(rc)) << 48);
      rank[eB] = (u16)rB;
    }
    return;
  }
  // ---- proj part (F = FN = 128, fp32 x, fp32 W; no LDS, no barriers) ----
  const int pb = blockIdx.x - EB2;
  const int w = t >> 6, l = t & 63;
  const int g = w * 4 + (l >> 4);
  const int rr = g * 8;
  const int c0 = (l & 15) * 4;
  const int row0 = pb * 128;

  int xoff[8];   // element offsets, tail rows clamped (stores guarded)
#pragma unroll
  for (int i = 0; i < 8; ++i) {
    int gr = row0 + rr + i;
    xoff[i] = (gr < NN ? gr : NN - 1) * FN;
  }

  float acc[8][4];
#pragma unroll
  for (int i = 0; i < 8; ++i)
#pragma unroll
    for (int j = 0; j < 4; ++j) acc[i][j] = 0.f;

  for (int k = 0; k < FN; k += 4) {
    float wv[4][4];
#pragma unroll
    for (int kk = 0; kk < 4; ++kk) {
      float4 wq = *(const float4*)(W + (k + kk) * HD + c0);
      wv[kk][0] = wq.x; wv[kk][1] = wq.y; wv[kk][2] = wq.z; wv[kk][3] = wq.w;
    }
#pragma unroll
    for (int i = 0; i < 8; ++i) {
      float4 a = *(const float4*)(x + xoff[i] + k);
#pragma unroll
      for (int j = 0; j < 4; ++j)
        acc[i][j] += a.x * wv[0][j] + a.y * wv[1][j] + a.z * wv[2][j] + a.w * wv[3][j];
    }
  }

  float as4[4], ad4[4];
#pragma unroll
  for (int j = 0; j < 4; ++j) { as4[j] = asv[c0 + j]; ad4[j] = adv[c0 + j]; }
#pragma unroll
  for (int i = 0; i < 8; ++i) {
    int gr = row0 + rr + i;
    float ps = 0.f, pd = 0.f;
#pragma unroll
    for (int j = 0; j < 4; ++j) {
      ps += acc[i][j] * as4[j];
      pd += acc[i][j] * ad4[j];
    }
#pragma unroll
    for (int off = 1; off < 16; off <<= 1) {
      ps += __shfl_xor(ps, off);
      pd += __shfl_xor(pd, off);
    }
    if (gr < NN) {
      union { __half2 h2[2]; float2 f2; } u;
      u.h2[0] = __floats2half2_rn(acc[i][0], acc[i][1]);
      u.h2[1] = __floats2half2_rn(acc[i][2], acc[i][3]);
      *(float2*)(xph + (size_t)gr * HD + c0) = u.f2;
      if ((l & 15) == 0) { ssrc[gr] = ps; sdst[gr] = pd; }
    }
  }
}

// ---------------- 2-phase parallel scan --------------------------------------
__global__ __launch_bounds__(256) void k_scanA(const int* __restrict__ deg,
                                               int* __restrict__ bsum) {
  __shared__ int ws[4];
  const int t = threadIdx.x, lane = t & 63, wid = t >> 6;
  const int i0 = blockIdx.x * 1024 + t * 4;
  int s = 0;
#pragma unroll
  for (int j = 0; j < 4; ++j) {
    int i = i0 + j;
    if (i < NN) s += deg[i];
  }
#pragma unroll
  for (int off = 32; off; off >>= 1) s += __shfl_xor(s, off);
  if (lane == 0) ws[wid] = s;
  __syncthreads();
  if (t == 0) bsum[blockIdx.x] = ws[0] + ws[1] + ws[2] + ws[3];
}

__global__ __launch_bounds__(256) void k_scanB(const int* __restrict__ deg,
                                               const int* __restrict__ bsum,
                                               int* __restrict__ row_ptr) {
  __shared__ int blockOff;
  __shared__ int wOff[4];
  const int b = blockIdx.x;
  const int t = threadIdx.x, lane = t & 63, wid = t >> 6;
  if (t < 64) {
    int v = (t < NB) ? bsum[t] : 0;
    int p = v;
#pragma unroll
    for (int off = 1; off < 64; off <<= 1) {
      int u = __shfl_up(p, off);
      if (lane >= off) p += u;
    }
    if (t == b) blockOff = p - v;
    if (b == 0 && t == NB - 1) row_ptr[NN] = p;
  }
  __syncthreads();
  const int i0 = b * 1024 + t * 4;
  int v[4];
#pragma unroll
  for (int j = 0; j < 4; ++j) {
    int i = i0 + j;
    v[j] = (i < NN) ? deg[i] : 0;
  }
  int s = v[0] + v[1] + v[2] + v[3];
  int p = s;
#pragma unroll
  for (int off = 1; off < 64; off <<= 1) {
    int u = __shfl_up(p, off);
    if (lane >= off) p += u;
  }
  if (lane == 63) wOff[wid] = p;
  __syncthreads();
  int woff = 0;
  for (int wq = 0; wq < wid; ++wq) woff += wOff[wq];
  int excl = blockOff + woff + (p - s);
#pragma unroll
  for (int j = 0; j < 4; ++j) {
    int i = i0 + j;
    if (i < NN) row_ptr[i] = excl;
    excl += v[j];
  }
}

// ---------------- light scatter: coalesced reads -> one random 8B write ------
__global__ void k_scatter(const int* __restrict__ dstA, const u16* __restrict__ rank,
                          const int* __restrict__ row_ptr, const u64* __restrict__ trec,
                          u64* __restrict__ aos) {
  const int e = blockIdx.x * blockDim.x + threadIdx.x;
  if (e >= NE) return;
  aos[row_ptr[dstA[e]] + (int)rank[e]] = trec[e];
}

// ------ fused: segment-softmax aggregate + NEXT-layer projection -------------
// 8 nodes per wave, 8 lanes per node (R11/R14 winning layout), chunk=16.
template <int TSEL>
__global__ __launch_bounds__(256) void k_agg_proj(
    const int* __restrict__ row_ptr, const u64* __restrict__ aos,
    const __half* __restrict__ xin, const float* __restrict__ ssrc_in,
    const float* __restrict__ sdst_in, const float* __restrict__ bias,
    const float* __restrict__ Wn, const float* __restrict__ asn,
    const float* __restrict__ adn, __half* __restrict__ xout,
    float* __restrict__ ssrc_out, float* __restrict__ sdst_out) {
  __shared__ __half swh[HD * HD];  // 8 KB, next-layer W in fp16
  const int t = threadIdx.x;
  for (int i = t; i < HD * HD; i += 256) swh[i] = __float2half_rn(Wn[i]);

  const int gw = (blockIdx.x * blockDim.x + t) >> 6;
  const int lane = t & 63;
  const int g = lane >> 3;
  const int q = lane & 7;
  const int n = gw * 8 + g;
  const bool act = n < NN;
  int beg = 0, end = 0;
  float sd = 0.f;
  if (act) { beg = row_ptr[n]; end = row_ptr[n + 1]; sd = sdst_in[n]; }

  float dsum = 0.f;
  float4 o0 = make_float4(0.f, 0.f, 0.f, 0.f);
  float4 o1 = make_float4(0.f, 0.f, 0.f, 0.f);
  for (int base = beg; base < end; base += 16) {
    const int p0 = base + q, p1 = base + 8 + q;
    float pe0 = 0.f, pe1 = 0.f;
    int s0 = 0, s1 = 0;
    if (p0 < end) {
      u64 r = aos[p0];
      s0 = (int)(r & 0xFFFFu);
      float tt = __half2float(__ushort_as_half((u16)((r >> (16 * TSEL)) & 0xFFFFu)));
      float raw = ssrc_in[s0] + sd + tt;
      raw = raw > 0.f ? raw : 0.2f * raw;
      pe0 = __expf(raw);
    }
    if (p1 < end) {
      u64 r = aos[p1];
      s1 = (int)(r & 0xFFFFu);
      float tt = __half2float(__ushort_as_half((u16)((r >> (16 * TSEL)) & 0xFFFFu)));
      float raw = ssrc_in[s1] + sd + tt;
      raw = raw > 0.f ? raw : 0.2f * raw;
      pe1 = __expf(raw);
    }
    dsum += pe0 + pe1;
#pragma unroll
    for (int j = 0; j < 8; ++j) {
      const int sl = g * 8 + j;
      float pa = __shfl(pe0, sl);
      int sa = __shfl(s0, sl);
      float pb = __shfl(pe1, sl);
      int sb = __shfl(s1, sl);
      union { float4 f4; __half2 h2[4]; } ua, ub;
      ua.f4 = ((const float4*)(xin + (size_t)sa * HD))[q];
      ub.f4 = ((const float4*)(xin + (size_t)sb * HD))[q];
      float2 a0 = __half22float2(ua.h2[0]);
      float2 a1 = __half22float2(ua.h2[1]);
      float2 a2 = __half22float2(ua.h2[2]);
      float2 a3 = __half22float2(ua.h2[3]);
      o0.x += pa * a0.x; o0.y += pa * a0.y; o0.z += pa * a1.x; o0.w += pa * a1.y;
      o1.x += pa * a2.x; o1.y += pa * a2.y; o1.z += pa * a3.x; o1.w += pa * a3.y;
      float2 b0 = __half22float2(ub.h2[0]);
      float2 b1 = __half22float2(ub.h2[1]);
      float2 b2 = __half22float2(ub.h2[2]);
      float2 b3 = __half22float2(ub.h2[3]);
      o0.x += pb * b0.x; o0.y += pb * b0.y; o0.z += pb * b1.x; o0.w += pb * b1.y;
      o1.x += pb * b2.x; o1.y += pb * b2.y; o1.z += pb * b3.x; o1.w += pb * b3.y;
    }
  }
#pragma unroll
  for (int off = 1; off < 8; off <<= 1) dsum += __shfl_xor(dsum, off);

  const float inv = 1.f / (dsum + 1e-16f);
  const float4 b0 = ((const float4*)bias)[q * 2];
  const float4 b1 = ((const float4*)bias)[q * 2 + 1];
  float vreg[8];
  vreg[0] = fmaxf(o0.x * inv + b0.x, 0.f);
  vreg[1] = fmaxf(o0.y * inv + b0.y, 0.f);
  vreg[2] = fmaxf(o0.z * inv + b0.z, 0.f);
  vreg[3] = fmaxf(o0.w * inv + b0.w, 0.f);
  vreg[4] = fmaxf(o1.x * inv + b1.x, 0.f);
  vreg[5] = fmaxf(o1.y * inv + b1.y, 0.f);
  vreg[6] = fmaxf(o1.z * inv + b1.z, 0.f);
  vreg[7] = fmaxf(o1.w * inv + b1.w, 0.f);

  __syncthreads();  // swh ready (all threads reach; no early returns above)

  float out8[8] = {0.f, 0.f, 0.f, 0.f, 0.f, 0.f, 0.f, 0.f};
#pragma unroll
  for (int kq = 0; kq < 8; ++kq) {
#pragma unroll
    for (int m = 0; m < 8; ++m) {
      float vb = __shfl(vreg[m], (lane & 56) | kq);
      union { float4 f4; __half2 h2[4]; } uw;
      uw.f4 = *(const float4*)(swh + (kq * 8 + m) * HD + q * 8);
      float2 w0 = __half22float2(uw.h2[0]);
      float2 w1 = __half22float2(uw.h2[1]);
      float2 w2 = __half22float2(uw.h2[2]);
      float2 w3 = __half22float2(uw.h2[3]);
      out8[0] += vb * w0.x; out8[1] += vb * w0.y;
      out8[2] += vb * w1.x; out8[3] += vb * w1.y;
      out8[4] += vb * w2.x; out8[5] += vb * w2.y;
      out8[6] += vb * w3.x; out8[7] += vb * w3.y;
    }
  }

  float ps = 0.f, pd = 0.f;
#pragma unroll
  for (int j = 0; j < 8; ++j) {
    ps += out8[j] * asn[q * 8 + j];
    pd += out8[j] * adn[q * 8 + j];
  }
#pragma unroll
  for (int off = 1; off < 8; off <<= 1) {
    ps += __shfl_xor(ps, off);
    pd += __shfl_xor(pd, off);
  }

  if (!act) return;
  union { float4 f4; __half2 h2[4]; } wv;
  wv.h2[0] = __floats2half2_rn(out8[0], out8[1]);
  wv.h2[1] = __floats2half2_rn(out8[2], out8[3]);
  wv.h2[2] = __floats2half2_rn(out8[4], out8[5]);
  wv.h2[3] = __floats2half2_rn(out8[6], out8[7]);
  ((float4*)(xout + (size_t)n * HD))[q] = wv.f4;
  if (q == 0) { ssrc_out[n] = ps; sdst_out[n] = pd; }
}

// ---------------- final: aggregate + head (val@Wc + bc) ----------------------
template <int TSEL>
__global__ __launch_bounds__(256) void k_agg_head(
    const int* __restrict__ row_ptr, const u64* __restrict__ aos,
    const __half* __restrict__ xin, const float* __restrict__ ssrc_in,
    const float* __restrict__ sdst_in, const float* __restrict__ bias,
    const float* __restrict__ Wc, const float* __restrict__ bc,
    float* __restrict__ outf) {
  const int gw = (blockIdx.x * blockDim.x + threadIdx.x) >> 6;
  const int lane = threadIdx.x & 63;
  const int g = lane >> 3;
  const int q = lane & 7;
  const int n = gw * 8 + g;
  const bool act = n < NN;
  int beg = 0, end = 0;
  float sd = 0.f;
  if (act) { beg = row_ptr[n]; end = row_ptr[n + 1]; sd = sdst_in[n]; }

  float dsum = 0.f;
  float4 o0 = make_float4(0.f, 0.f, 0.f, 0.f);
  float4 o1 = make_float4(0.f, 0.f, 0.f, 0.f);
  for (int base = beg; base < end; base += 16) {
    const int p0 = base + q, p1 = base + 8 + q;
    float pe0 = 0.f, pe1 = 0.f;
    int s0 = 0, s1 = 0;
    if (p0 < end) {
      u64 r = aos[p0];
      s0 = (int)(r & 0xFFFFu);
      float tt = __half2float(__ushort_as_half((u16)((r >> (16 * TSEL)) & 0xFFFFu)));
      float raw = ssrc_in[s0] + sd + tt;
      raw = raw > 0.f ? raw : 0.2f * raw;
      pe0 = __expf(raw);
    }
    if (p1 < end) {
      u64 r = aos[p1];
      s1 = (int)(r & 0xFFFFu);
      float tt = __half2float(__ushort_as_half((u16)((r >> (16 * TSEL)) & 0xFFFFu)));
      float raw = ssrc_in[s1] + sd + tt;
      raw = raw > 0.f ? raw : 0.2f * raw;
      pe1 = __expf(raw);
    }
    dsum += pe0 + pe1;
#pragma unroll
    for (int j = 0; j < 8; ++j) {
      const int sl = g * 8 + j;
      float pa = __shfl(pe0, sl);
      int sa = __shfl(s0, sl);
      float pb = __shfl(pe1, sl);
      int sb = __shfl(s1, sl);
      union { float4 f4; __half2 h2[4]; } ua, ub;
      ua.f4 = ((const float4*)(xin + (size_t)sa * HD))[q];
      ub.f4 = ((const float4*)(xin + (size_t)sb * HD))[q];
      float2 a0 = __half22float2(ua.h2[0]);
      float2 a1 = __half22float2(ua.h2[1]);
      float2 a2 = __half22float2(ua.h2[2]);
      float2 a3 = __half22float2(ua.h2[3]);
      o0.x += pa * a0.x; o0.y += pa * a0.y; o0.z += pa * a1.x; o0.w += pa * a1.y;
      o1.x += pa * a2.x; o1.y += pa * a2.y; o1.z += pa * a3.x; o1.w += pa * a3.y;
      float2 b0 = __half22float2(ub.h2[0]);
      float2 b1 = __half22float2(ub.h2[1]);
      float2 b2 = __half22float2(ub.h2[2]);
      float2 b3 = __half22float2(ub.h2[3]);
      o0.x += pb * b0.x; o0.y += pb * b0.y; o0.z += pb * b1.x; o0.w += pb * b1.y;
      o1.x += pb * b2.x; o1.y += pb * b2.y; o1.z += pb * b3.x; o1.w += pb * b3.y;
    }
  }
#pragma unroll
  for (int off = 1; off < 8; off <<= 1) dsum += __shfl_xor(dsum, off);

  if (!act) return;
  const float inv = 1.f / (dsum + 1e-16f);
  const float4 b0 = ((const float4*)bias)[q * 2];
  const float4 b1 = ((const float4*)bias)[q * 2 + 1];
  const float4 w0 = ((const float4*)Wc)[q * 2];
  const float4 w1 = ((const float4*)Wc)[q * 2 + 1];
  float c = fmaxf(o0.x * inv + b0.x, 0.f) * w0.x +
            fmaxf(o0.y * inv + b0.y, 0.f) * w0.y +
            fmaxf(o0.z * inv + b0.z, 0.f) * w0.z +
            fmaxf(o0.w * inv + b0.w, 0.f) * w0.w +
            fmaxf(o1.x * inv + b1.x, 0.f) * w1.x +
            fmaxf(o1.y * inv + b1.y, 0.f) * w1.y +
            fmaxf(o1.z * inv + b1.z, 0.f) * w1.z +
            fmaxf(o1.w * inv + b1.w, 0.f) * w1.w;
#pragma unroll
  for (int off = 1; off < 8; off <<= 1) c += __shfl_xor(c, off);
  if (q == 0) outf[n] = c + bc[0];
}

// ---------------- host-side orchestration ------------------------------------
extern "C" void kernel_launch(void* const* d_in, const int* in_sizes, int n_in,
                              void* d_out, int out_size, void* d_ws, size_t ws_size,
                              hipStream_t stream) {
  const float* x     = (const float*)d_in[0];
  const int*   ei    = (const int*)d_in[1];
  const float* eattr = (const float*)d_in[2];
  const float* W1  = (const float*)d_in[3];
  const float* We1 = (const float*)d_in[4];
  const float* as1 = (const float*)d_in[5];
  const float* ad1 = (const float*)d_in[6];
  const float* ae1 = (const float*)d_in[7];
  const float* b1  = (const float*)d_in[8];
  const float* W2  = (const float*)d_in[9];
  const float* We2 = (const float*)d_in[10];
  const float* as2 = (const float*)d_in[11];
  const float* ad2 = (const float*)d_in[12];
  const float* ae2 = (const float*)d_in[13];
  const float* b2  = (const float*)d_in[14];
  const float* W3  = (const float*)d_in[15];
  const float* We3 = (const float*)d_in[16];
  const float* as3 = (const float*)d_in[17];
  const float* ad3 = (const float*)d_in[18];
  const float* ae3 = (const float*)d_in[19];
  const float* b3  = (const float*)d_in[20];
  const float* Wc  = (const float*)d_in[21];
  const float* bc  = (const float*)d_in[22];

  const int* srcA = ei;        // edge_index[0]
  const int* dstA = ei + NE;   // edge_index[1]
  float* outf = (float*)d_out;

  char* w = (char*)d_ws;
  auto alloc = [&](size_t bytes) {
    char* p = w;
    w += (bytes + 255) & ~(size_t)255;
    return p;
  };
  float* v123 = (float*)alloc(96 * 4);
  u64* aos = (u64*)alloc((size_t)NE * 8);
  u64* trec = (u64*)alloc((size_t)NE * 8);
  u16* rank = (u16*)alloc((size_t)NE * 2);
  int* row_ptr = (int*)alloc((size_t)(NN + 1) * 4);
  int* deg = (int*)alloc((size_t)NN * 4);
  int* bsum = (int*)alloc((size_t)NB * 4);
  __half* xpA = (__half*)alloc((size_t)NN * HD * 2);
  __half* xpB = (__half*)alloc((size_t)NN * HD * 2);
  float* ssrcA = (float*)alloc((size_t)NN * 4);
  float* sdstA = (float*)alloc((size_t)NN * 4);
  float* ssrcB = (float*)alloc((size_t)NN * 4);
  float* sdstB = (float*)alloc((size_t)NN * 4);

  const int gN = (NN + 255) / 256;
  const int gA = ((NN + 7) / 8 * 64 + 255) / 256;   // 8 nodes per wave

  k_vecs_zero<<<gN, 256, 0, stream>>>(We1, We2, We3, ae1, ae2, ae3, v123, deg);
  // edge blocks first (long pole), layer-1 GEMM co-dispatched behind
  k_mega6<<<EB2 + GP, 256, 0, stream>>>(x, W1, as1, ad1, xpA, ssrcA, sdstA,
                                        srcA, dstA, eattr, v123, deg, rank, trec);
  k_scanA<<<NB, 256, 0, stream>>>(deg, bsum);
  k_scanB<<<NB, 256, 0, stream>>>(deg, bsum, row_ptr);
  k_scatter<<<GE, 256, 0, stream>>>(dstA, rank, row_ptr, trec, aos);
  // layer 1 aggregate + layer-2 projection (fused)
  k_agg_proj<1><<<gA, 256, 0, stream>>>(row_ptr, aos, xpA, ssrcA, sdstA, b1,
                                        W2, as2, ad2, xpB, ssrcB, sdstB);
  // layer 2 aggregate + layer-3 projection (fused)
  k_agg_proj<2><<<gA, 256, 0, stream>>>(row_ptr, aos, xpB, ssrcB, sdstB, b2,
                                        W3, as3, ad3, xpA, ssrcA, sdstA);
  // layer 3 aggregate + head
  k_agg_head<3><<<gA, 256, 0, stream>>>(row_ptr, aos, xpA, ssrcA, sdstA, b3,
                                        Wc, bc, outf);
}

// Round 8
// 164.369 us; speedup vs baseline: 1.0977x; 1.0977x over previous
//
#include <hip/hip_runtime.h>
#include <hip/hip_fp16.h>
#include <math.h>

#define NN 50000
#define NE 800000
#define FN 128
#define FE 32
#define HD 64
#define NB 49   // scan blocks: ceil(NN/1024)
#define GP ((NN + 127) / 128)    // proj blocks (128 rows each)
#define EB3 ((NE + 1023) / 1024) // 782 edge blocks: 1024 edges, 4 chunks of 256
#define GE ((NE + 255) / 256)    // scatter blocks

typedef unsigned long long u64;
typedef unsigned short u16;
typedef const void __attribute__((address_space(1)))* gas_t;
typedef void __attribute__((address_space(3)))* las_t;

// ---------------- K0: fold edge chains into v1,v2,v3 + zero deg --------------
__global__ void k_vecs_zero(const float* __restrict__ We1, const float* __restrict__ We2,
                            const float* __restrict__ We3, const float* __restrict__ ae1,
                            const float* __restrict__ ae2, const float* __restrict__ ae3,
                            float* __restrict__ v123, int* __restrict__ deg) {
  const int i = blockIdx.x * blockDim.x + threadIdx.x;
  if (i < NN) deg[i] = 0;
  if (blockIdx.x != 0) return;
  __shared__ float u2[HD], u3[HD], u23[HD];
  const int t = threadIdx.x;
  if (t < HD) {
    float s2 = 0.f, s3 = 0.f;
    for (int j = 0; j < HD; ++j) {
      s2 += We2[t * HD + j] * ae2[j];
      s3 += We3[t * HD + j] * ae3[j];
    }
    u2[t] = s2; u3[t] = s3;
  }
  __syncthreads();
  if (t < HD) {
    float s23 = 0.f;
    for (int j = 0; j < HD; ++j) s23 += We2[t * HD + j] * u3[j];
    u23[t] = s23;
  }
  __syncthreads();
  if (t < FE) {
    float a = 0.f, b = 0.f, c = 0.f;
    for (int j = 0; j < HD; ++j) {
      float w = We1[t * HD + j];
      a += w * ae1[j];
      b += w * u2[j];
      c += w * u23[j];
    }
    v123[t] = a; v123[32 + t] = b; v123[64 + t] = c;
  }
}

// ---- mega7: [0,GP) LDS-free layer-1 GEMM | rest: DMA-staged edge phase ------
// Edge ingestion via __builtin_amdgcn_global_load_lds (16B async DMA, no VGPR
// round trip) — the ONE path untested across R2-R7's 67-96us invariant floor.
// 4 chunks x 256 edges (32KB LDS each); all 4 chunks' dst/src/atomics issued
// up-front; compute reads LDS rows in XOR-rotated column order (jj=j^(t&7)),
// which spreads the D=128 row-major read across all 32 banks (8cy structural
// floor vs 64cy linear). LDS 33KB -> 4 blocks/CU == R5's VGPR-68 16-wave cap,
// so occupancy is held constant; only the ingestion mechanism changes.
__global__ __launch_bounds__(256) void k_mega7(
    const float* __restrict__ x, const float* __restrict__ W,
    const float* __restrict__ asv, const float* __restrict__ adv,
    __half* __restrict__ xph, float* __restrict__ ssrc, float* __restrict__ sdst,
    const int* __restrict__ srcA, const int* __restrict__ dstA,
    const float* __restrict__ eattr, const float* __restrict__ v123,
    int* __restrict__ deg, u16* __restrict__ rank, u64* __restrict__ trec) {
  __shared__ float sbuf[8192];   // 32KB: one 256-edge chunk
  __shared__ float sv[96];       // v1|v2|v3 folded vectors
  const int t = threadIdx.x;
  if (blockIdx.x >= GP) {
    const int kb = blockIdx.x - GP;
    const int base = kb * 1024;
    const int w = t >> 6, lane = t & 63;
    if (t < 96) sv[t] = v123[t];

    // all 4 chunks' index loads + returning atomics in flight up front
    int sE[4], rE[4];
#pragma unroll
    for (int c = 0; c < 4; ++c) {
      const int e = base + c * 256 + t;
      sE[c] = 0; rE[c] = 0;
      if (e < NE) {
        const int d = dstA[e];
        sE[c] = srcA[e];
        rE[c] = atomicAdd(&deg[d], 1);
      }
    }

    const int jrot = t & 7;
#pragma unroll 1
    for (int c = 0; c < 4; ++c) {
      const bool cv = (base + c * 256) < NE;   // block-uniform (NE%256==0)
      if (cv) {
        // wave w DMAs 8 x 1KB contiguous segments of this chunk into LDS
        const size_t gf = (size_t)(base + c * 256) * FE;
#pragma unroll
        for (int i = 0; i < 8; ++i) {
          const int seg = w * 8 + i;
          const float* g = eattr + gf + seg * 256 + lane * 4;
          __builtin_amdgcn_global_load_lds((gas_t)g, (las_t)(sbuf + seg * 256),
                                           16, 0, 0);
        }
      }
      __syncthreads();   // drains DMA (vmcnt) + sv stage on c==0
      if (cv) {
        const float* row = sbuf + (t << 5);
        float a = 0.f, b = 0.f, cc = 0.f;
#pragma unroll
        for (int j = 0; j < 8; ++j) {
          const int jj = j ^ jrot;             // order-invariant dot; kills
          const float4 xv = *(const float4*)(row + jj * 4);   // bank conflicts
          const float4 w1 = *(const float4*)(sv + jj * 4);
          const float4 w2 = *(const float4*)(sv + 32 + jj * 4);
          const float4 w3 = *(const float4*)(sv + 64 + jj * 4);
          a  += xv.x * w1.x + xv.y * w1.y + xv.z * w1.z + xv.w * w1.w;
          b  += xv.x * w2.x + xv.y * w2.y + xv.z * w2.z + xv.w * w2.w;
          cc += xv.x * w3.x + xv.y * w3.y + xv.z * w3.z + xv.w * w3.w;
        }
        const int e = base + c * 256 + t;
        trec[e] = (u64)(u16)sE[c]
                | ((u64)__half_as_ushort(__float2half_rn(a)) << 16)
                | ((u64)__half_as_ushort(__float2half_rn(b)) << 32)
                | ((u64)__half_as_ushort(__float2half_rn(cc)) << 48);
        rank[e] = (u16)rE[c];
      }
      __syncthreads();   // buffer safe to overwrite next chunk
    }
    return;
  }
  // ---- proj part (F = FN = 128, fp32 x, fp32 W; no LDS use, no barriers) ----
  const int w = t >> 6, l = t & 63;
  const int g = w * 4 + (l >> 4);
  const int rr = g * 8;
  const int c0 = (l & 15) * 4;
  const int row0 = blockIdx.x * 128;

  int xoff[8];   // element offsets, tail rows clamped (stores guarded)
#pragma unroll
  for (int i = 0; i < 8; ++i) {
    int gr = row0 + rr + i;
    xoff[i] = (gr < NN ? gr : NN - 1) * FN;
  }

  float acc[8][4];
#pragma unroll
  for (int i = 0; i < 8; ++i)
#pragma unroll
    for (int j = 0; j < 4; ++j) acc[i][j] = 0.f;

  for (int k = 0; k < FN; k += 4) {
    float wv[4][4];
#pragma unroll
    for (int kk = 0; kk < 4; ++kk) {
      float4 wq = *(const float4*)(W + (k + kk) * HD + c0);
      wv[kk][0] = wq.x; wv[kk][1] = wq.y; wv[kk][2] = wq.z; wv[kk][3] = wq.w;
    }
#pragma unroll
    for (int i = 0; i < 8; ++i) {
      float4 a = *(const float4*)(x + xoff[i] + k);
#pragma unroll
      for (int j = 0; j < 4; ++j)
        acc[i][j] += a.x * wv[0][j] + a.y * wv[1][j] + a.z * wv[2][j] + a.w * wv[3][j];
    }
  }

  float as4[4], ad4[4];
#pragma unroll
  for (int j = 0; j < 4; ++j) { as4[j] = asv[c0 + j]; ad4[j] = adv[c0 + j]; }
#pragma unroll
  for (int i = 0; i < 8; ++i) {
    int gr = row0 + rr + i;
    float ps = 0.f, pd = 0.f;
#pragma unroll
    for (int j = 0; j < 4; ++j) {
      ps += acc[i][j] * as4[j];
      pd += acc[i][j] * ad4[j];
    }
#pragma unroll
    for (int off = 1; off < 16; off <<= 1) {
      ps += __shfl_xor(ps, off);
      pd += __shfl_xor(pd, off);
    }
    if (gr < NN) {
      union { __half2 h2[2]; float2 f2; } u;
      u.h2[0] = __floats2half2_rn(acc[i][0], acc[i][1]);
      u.h2[1] = __floats2half2_rn(acc[i][2], acc[i][3]);
      *(float2*)(xph + (size_t)gr * HD + c0) = u.f2;
      if ((l & 15) == 0) { ssrc[gr] = ps; sdst[gr] = pd; }
    }
  }
}

// ---------------- 2-phase parallel scan --------------------------------------
__global__ __launch_bounds__(256) void k_scanA(const int* __restrict__ deg,
                                               int* __restrict__ bsum) {
  __shared__ int ws[4];
  const int t = threadIdx.x, lane = t & 63, wid = t >> 6;
  const int i0 = blockIdx.x * 1024 + t * 4;
  int s = 0;
#pragma unroll
  for (int j = 0; j < 4; ++j) {
    int i = i0 + j;
    if (i < NN) s += deg[i];
  }
#pragma unroll
  for (int off = 32; off; off >>= 1) s += __shfl_xor(s, off);
  if (lane == 0) ws[wid] = s;
  __syncthreads();
  if (t == 0) bsum[blockIdx.x] = ws[0] + ws[1] + ws[2] + ws[3];
}

__global__ __launch_bounds__(256) void k_scanB(const int* __restrict__ deg,
                                               const int* __restrict__ bsum,
                                               int* __restrict__ row_ptr) {
  __shared__ int blockOff;
  __shared__ int wOff[4];
  const int b = blockIdx.x;
  const int t = threadIdx.x, lane = t & 63, wid = t >> 6;
  if (t < 64) {
    int v = (t < NB) ? bsum[t] : 0;
    int p = v;
#pragma unroll
    for (int off = 1; off < 64; off <<= 1) {
      int u = __shfl_up(p, off);
      if (lane >= off) p += u;
    }
    if (t == b) blockOff = p - v;
    if (b == 0 && t == NB - 1) row_ptr[NN] = p;
  }
  __syncthreads();
  const int i0 = b * 1024 + t * 4;
  int v[4];
#pragma unroll
  for (int j = 0; j < 4; ++j) {
    int i = i0 + j;
    v[j] = (i < NN) ? deg[i] : 0;
  }
  int s = v[0] + v[1] + v[2] + v[3];
  int p = s;
#pragma unroll
  for (int off = 1; off < 64; off <<= 1) {
    int u = __shfl_up(p, off);
    if (lane >= off) p += u;
  }
  if (lane == 63) wOff[wid] = p;
  __syncthreads();
  int woff = 0;
  for (int wq = 0; wq < wid; ++wq) woff += wOff[wq];
  int excl = blockOff + woff + (p - s);
#pragma unroll
  for (int j = 0; j < 4; ++j) {
    int i = i0 + j;
    if (i < NN) row_ptr[i] = excl;
    excl += v[j];
  }
}

// ---------------- light scatter: coalesced reads -> one random 8B write ------
__global__ void k_scatter(const int* __restrict__ dstA, const u16* __restrict__ rank,
                          const int* __restrict__ row_ptr, const u64* __restrict__ trec,
                          u64* __restrict__ aos) {
  const int e = blockIdx.x * blockDim.x + threadIdx.x;
  if (e >= NE) return;
  aos[row_ptr[dstA[e]] + (int)rank[e]] = trec[e];
}

// ------ fused: segment-softmax aggregate + NEXT-layer projection -------------
// 8 nodes per wave, 8 lanes per node (R11/R14 winning layout), chunk=16.
template <int TSEL>
__global__ __launch_bounds__(256) void k_agg_proj(
    const int* __restrict__ row_ptr, const u64* __restrict__ aos,
    const __half* __restrict__ xin, const float* __restrict__ ssrc_in,
    const float* __restrict__ sdst_in, const float* __restrict__ bias,
    const float* __restrict__ Wn, const float* __restrict__ asn,
    const float* __restrict__ adn, __half* __restrict__ xout,
    float* __restrict__ ssrc_out, float* __restrict__ sdst_out) {
  __shared__ __half swh[HD * HD];  // 8 KB, next-layer W in fp16
  const int t = threadIdx.x;
  for (int i = t; i < HD * HD; i += 256) swh[i] = __float2half_rn(Wn[i]);

  const int gw = (blockIdx.x * blockDim.x + t) >> 6;
  const int lane = t & 63;
  const int g = lane >> 3;
  const int q = lane & 7;
  const int n = gw * 8 + g;
  const bool act = n < NN;
  int beg = 0, end = 0;
  float sd = 0.f;
  if (act) { beg = row_ptr[n]; end = row_ptr[n + 1]; sd = sdst_in[n]; }

  float dsum = 0.f;
  float4 o0 = make_float4(0.f, 0.f, 0.f, 0.f);
  float4 o1 = make_float4(0.f, 0.f, 0.f, 0.f);
  for (int base = beg; base < end; base += 16) {
    const int p0 = base + q, p1 = base + 8 + q;
    float pe0 = 0.f, pe1 = 0.f;
    int s0 = 0, s1 = 0;
    if (p0 < end) {
      u64 r = aos[p0];
      s0 = (int)(r & 0xFFFFu);
      float tt = __half2float(__ushort_as_half((u16)((r >> (16 * TSEL)) & 0xFFFFu)));
      float raw = ssrc_in[s0] + sd + tt;
      raw = raw > 0.f ? raw : 0.2f * raw;
      pe0 = __expf(raw);
    }
    if (p1 < end) {
      u64 r = aos[p1];
      s1 = (int)(r & 0xFFFFu);
      float tt = __half2float(__ushort_as_half((u16)((r >> (16 * TSEL)) & 0xFFFFu)));
      float raw = ssrc_in[s1] + sd + tt;
      raw = raw > 0.f ? raw : 0.2f * raw;
      pe1 = __expf(raw);
    }
    dsum += pe0 + pe1;
#pragma unroll
    for (int j = 0; j < 8; ++j) {
      const int sl = g * 8 + j;
      float pa = __shfl(pe0, sl);
      int sa = __shfl(s0, sl);
      float pb = __shfl(pe1, sl);
      int sb = __shfl(s1, sl);
      union { float4 f4; __half2 h2[4]; } ua, ub;
      ua.f4 = ((const float4*)(xin + (size_t)sa * HD))[q];
      ub.f4 = ((const float4*)(xin + (size_t)sb * HD))[q];
      float2 a0 = __half22float2(ua.h2[0]);
      float2 a1 = __half22float2(ua.h2[1]);
      float2 a2 = __half22float2(ua.h2[2]);
      float2 a3 = __half22float2(ua.h2[3]);
      o0.x += pa * a0.x; o0.y += pa * a0.y; o0.z += pa * a1.x; o0.w += pa * a1.y;
      o1.x += pa * a2.x; o1.y += pa * a2.y; o1.z += pa * a3.x; o1.w += pa * a3.y;
      float2 b0 = __half22float2(ub.h2[0]);
      float2 b1 = __half22float2(ub.h2[1]);
      float2 b2 = __half22float2(ub.h2[2]);
      float2 b3 = __half22float2(ub.h2[3]);
      o0.x += pb * b0.x; o0.y += pb * b0.y; o0.z += pb * b1.x; o0.w += pb * b1.y;
      o1.x += pb * b2.x; o1.y += pb * b2.y; o1.z += pb * b3.x; o1.w += pb * b3.y;
    }
  }
#pragma unroll
  for (int off = 1; off < 8; off <<= 1) dsum += __shfl_xor(dsum, off);

  const float inv = 1.f / (dsum + 1e-16f);
  const float4 b0 = ((const float4*)bias)[q * 2];
  const float4 b1 = ((const float4*)bias)[q * 2 + 1];
  float vreg[8];
  vreg[0] = fmaxf(o0.x * inv + b0.x, 0.f);
  vreg[1] = fmaxf(o0.y * inv + b0.y, 0.f);
  vreg[2] = fmaxf(o0.z * inv + b0.z, 0.f);
  vreg[3] = fmaxf(o0.w * inv + b0.w, 0.f);
  vreg[4] = fmaxf(o1.x * inv + b1.x, 0.f);
  vreg[5] = fmaxf(o1.y * inv + b1.y, 0.f);
  vreg[6] = fmaxf(o1.z * inv + b1.z, 0.f);
  vreg[7] = fmaxf(o1.w * inv + b1.w, 0.f);

  __syncthreads();  // swh ready (all threads reach; no early returns above)

  float out8[8] = {0.f, 0.f, 0.f, 0.f, 0.f, 0.f, 0.f, 0.f};
#pragma unroll
  for (int kq = 0; kq < 8; ++kq) {
#pragma unroll
    for (int m = 0; m < 8; ++m) {
      float vb = __shfl(vreg[m], (lane & 56) | kq);
      union { float4 f4; __half2 h2[4]; } uw;
      uw.f4 = *(const float4*)(swh + (kq * 8 + m) * HD + q * 8);
      float2 w0 = __half22float2(uw.h2[0]);
      float2 w1 = __half22float2(uw.h2[1]);
      float2 w2 = __half22float2(uw.h2[2]);
      float2 w3 = __half22float2(uw.h2[3]);
      out8[0] += vb * w0.x; out8[1] += vb * w0.y;
      out8[2] += vb * w1.x; out8[3] += vb * w1.y;
      out8[4] += vb * w2.x; out8[5] += vb * w2.y;
      out8[6] += vb * w3.x; out8[7] += vb * w3.y;
    }
  }

  float ps = 0.f, pd = 0.f;
#pragma unroll
  for (int j = 0; j < 8; ++j) {
    ps += out8[j] * asn[q * 8 + j];
    pd += out8[j] * adn[q * 8 + j];
  }
#pragma unroll
  for (int off = 1; off < 8; off <<= 1) {
    ps += __shfl_xor(ps, off);
    pd += __shfl_xor(pd, off);
  }

  if (!act) return;
  union { float4 f4; __half2 h2[4]; } wv;
  wv.h2[0] = __floats2half2_rn(out8[0], out8[1]);
  wv.h2[1] = __floats2half2_rn(out8[2], out8[3]);
  wv.h2[2] = __floats2half2_rn(out8[4], out8[5]);
  wv.h2[3] = __floats2half2_rn(out8[6], out8[7]);
  ((float4*)(xout + (size_t)n * HD))[q] = wv.f4;
  if (q == 0) { ssrc_out[n] = ps; sdst_out[n] = pd; }
}

// ---------------- final: aggregate + head (val@Wc + bc) ----------------------
template <int TSEL>
__global__ __launch_bounds__(256) void k_agg_head(
    const int* __restrict__ row_ptr, const u64* __restrict__ aos,
    const __half* __restrict__ xin, const float* __restrict__ ssrc_in,
    const float* __restrict__ sdst_in, const float* __restrict__ bias,
    const float* __restrict__ Wc, const float* __restrict__ bc,
    float* __restrict__ outf) {
  const int gw = (blockIdx.x * blockDim.x + threadIdx.x) >> 6;
  const int lane = threadIdx.x & 63;
  const int g = lane >> 3;
  const int q = lane & 7;
  const int n = gw * 8 + g;
  const bool act = n < NN;
  int beg = 0, end = 0;
  float sd = 0.f;
  if (act) { beg = row_ptr[n]; end = row_ptr[n + 1]; sd = sdst_in[n]; }

  float dsum = 0.f;
  float4 o0 = make_float4(0.f, 0.f, 0.f, 0.f);
  float4 o1 = make_float4(0.f, 0.f, 0.f, 0.f);
  for (int base = beg; base < end; base += 16) {
    const int p0 = base + q, p1 = base + 8 + q;
    float pe0 = 0.f, pe1 = 0.f;
    int s0 = 0, s1 = 0;
    if (p0 < end) {
      u64 r = aos[p0];
      s0 = (int)(r & 0xFFFFu);
      float tt = __half2float(__ushort_as_half((u16)((r >> (16 * TSEL)) & 0xFFFFu)));
      float raw = ssrc_in[s0] + sd + tt;
      raw = raw > 0.f ? raw : 0.2f * raw;
      pe0 = __expf(raw);
    }
    if (p1 < end) {
      u64 r = aos[p1];
      s1 = (int)(r & 0xFFFFu);
      float tt = __half2float(__ushort_as_half((u16)((r >> (16 * TSEL)) & 0xFFFFu)));
      float raw = ssrc_in[s1] + sd + tt;
      raw = raw > 0.f ? raw : 0.2f * raw;
      pe1 = __expf(raw);
    }
    dsum += pe0 + pe1;
#pragma unroll
    for (int j = 0; j < 8; ++j) {
      const int sl = g * 8 + j;
      float pa = __shfl(pe0, sl);
      int sa = __shfl(s0, sl);
      float pb = __shfl(pe1, sl);
      int sb = __shfl(s1, sl);
      union { float4 f4; __half2 h2[4]; } ua, ub;
      ua.f4 = ((const float4*)(xin + (size_t)sa * HD))[q];
      ub.f4 = ((const float4*)(xin + (size_t)sb * HD))[q];
      float2 a0 = __half22float2(ua.h2[0]);
      float2 a1 = __half22float2(ua.h2[1]);
      float2 a2 = __half22float2(ua.h2[2]);
      float2 a3 = __half22float2(ua.h2[3]);
      o0.x += pa * a0.x; o0.y += pa * a0.y; o0.z += pa * a1.x; o0.w += pa * a1.y;
      o1.x += pa * a2.x; o1.y += pa * a2.y; o1.z += pa * a3.x; o1.w += pa * a3.y;
      float2 b0 = __half22float2(ub.h2[0]);
      float2 b1 = __half22float2(ub.h2[1]);
      float2 b2 = __half22float2(ub.h2[2]);
      float2 b3 = __half22float2(ub.h2[3]);
      o0.x += pb * b0.x; o0.y += pb * b0.y; o0.z += pb * b1.x; o0.w += pb * b1.y;
      o1.x += pb * b2.x; o1.y += pb * b2.y; o1.z += pb * b3.x; o1.w += pb * b3.y;
    }
  }
#pragma unroll
  for (int off = 1; off < 8; off <<= 1) dsum += __shfl_xor(dsum, off);

  if (!act) return;
  const float inv = 1.f / (dsum + 1e-16f);
  const float4 b0 = ((const float4*)bias)[q * 2];
  const float4 b1 = ((const float4*)bias)[q * 2 + 1];
  const float4 w0 = ((const float4*)Wc)[q * 2];
  const float4 w1 = ((const float4*)Wc)[q * 2 + 1];
  float c = fmaxf(o0.x * inv + b0.x, 0.f) * w0.x +
            fmaxf(o0.y * inv + b0.y, 0.f) * w0.y +
            fmaxf(o0.z * inv + b0.z, 0.f) * w0.z +
            fmaxf(o0.w * inv + b0.w, 0.f) * w0.w +
            fmaxf(o1.x * inv + b1.x, 0.f) * w1.x +
            fmaxf(o1.y * inv + b1.y, 0.f) * w1.y +
            fmaxf(o1.z * inv + b1.z, 0.f) * w1.z +
            fmaxf(o1.w * inv + b1.w, 0.f) * w1.w;
#pragma unroll
  for (int off = 1; off < 8; off <<= 1) c += __shfl_xor(c, off);
  if (q == 0) outf[n] = c + bc[0];
}

// ---------------- host-side orchestration ------------------------------------
extern "C" void kernel_launch(void* const* d_in, const int* in_sizes, int n_in,
                              void* d_out, int out_size, void* d_ws, size_t ws_size,
                              hipStream_t stream) {
  const float* x     = (const float*)d_in[0];
  const int*   ei    = (const int*)d_in[1];
  const float* eattr = (const float*)d_in[2];
  const float* W1  = (const float*)d_in[3];
  const float* We1 = (const float*)d_in[4];
  const float* as1 = (const float*)d_in[5];
  const float* ad1 = (const float*)d_in[6];
  const float* ae1 = (const float*)d_in[7];
  const float* b1  = (const float*)d_in[8];
  const float* W2  = (const float*)d_in[9];
  const float* We2 = (const float*)d_in[10];
  const float* as2 = (const float*)d_in[11];
  const float* ad2 = (const float*)d_in[12];
  const float* ae2 = (const float*)d_in[13];
  const float* b2  = (const float*)d_in[14];
  const float* W3  = (const float*)d_in[15];
  const float* We3 = (const float*)d_in[16];
  const float* as3 = (const float*)d_in[17];
  const float* ad3 = (const float*)d_in[18];
  const float* ae3 = (const float*)d_in[19];
  const float* b3  = (const float*)d_in[20];
  const float* Wc  = (const float*)d_in[21];
  const float* bc  = (const float*)d_in[22];

  const int* srcA = ei;        // edge_index[0]
  const int* dstA = ei + NE;   // edge_index[1]
  float* outf = (float*)d_out;

  char* w = (char*)d_ws;
  auto alloc = [&](size_t bytes) {
    char* p = w;
    w += (bytes + 255) & ~(size_t)255;
    return p;
  };
  float* v123 = (float*)alloc(96 * 4);
  u64* aos = (u64*)alloc((size_t)NE * 8);
  u64* trec = (u64*)alloc((size_t)NE * 8);
  u16* rank = (u16*)alloc((size_t)NE * 2);
  int* row_ptr = (int*)alloc((size_t)(NN + 1) * 4);
  int* deg = (int*)alloc((size_t)NN * 4);
  int* bsum = (int*)alloc((size_t)NB * 4);
  __half* xpA = (__half*)alloc((size_t)NN * HD * 2);
  __half* xpB = (__half*)alloc((size_t)NN * HD * 2);
  float* ssrcA = (float*)alloc((size_t)NN * 4);
  float* sdstA = (float*)alloc((size_t)NN * 4);
  float* ssrcB = (float*)alloc((size_t)NN * 4);
  float* sdstB = (float*)alloc((size_t)NN * 4);

  const int gN = (NN + 255) / 256;
  const int gA = ((NN + 7) / 8 * 64 + 255) / 256;   // 8 nodes per wave

  k_vecs_zero<<<gN, 256, 0, stream>>>(We1, We2, We3, ae1, ae2, ae3, v123, deg);
  // layer-1 GEMM + DMA-staged edge {deg atomic, trec stream}, one dispatch
  k_mega7<<<GP + EB3, 256, 0, stream>>>(x, W1, as1, ad1, xpA, ssrcA, sdstA,
                                        srcA, dstA, eattr, v123, deg, rank, trec);
  k_scanA<<<NB, 256, 0, stream>>>(deg, bsum);
  k_scanB<<<NB, 256, 0, stream>>>(deg, bsum, row_ptr);
  k_scatter<<<GE, 256, 0, stream>>>(dstA, rank, row_ptr, trec, aos);
  // layer 1 aggregate + layer-2 projection (fused)
  k_agg_proj<1><<<gA, 256, 0, stream>>>(row_ptr, aos, xpA, ssrcA, sdstA, b1,
                                        W2, as2, ad2, xpB, ssrcB, sdstB);
  // layer 2 aggregate + layer-3 projection (fused)
  k_agg_proj<2><<<gA, 256, 0, stream>>>(row_ptr, aos, xpB, ssrcB, sdstB, b2,
                                        W3, as3, ad3, xpA, ssrcA, sdstA);
  // layer 3 aggregate + head
  k_agg_head<3><<<gA, 256, 0, stream>>>(row_ptr, aos, xpA, ssrcA, sdstA, b3,
                                        Wc, bc, outf);
}